// Round 16
// baseline (203.123 us; speedup 1.0000x reference)
//
#include <hip/hip_runtime.h>
#include <hip/hip_fp16.h>
#include <stdint.h>

// Problem constants (match reference)
#define N_NODES  50000
#define N_EDGES  800000
#define D        256
#define D_OUT    16
#define N_GRAPHS 128
#define NB_SCAN  196        // 196*256 = 50176 >= N_NODES+1

// JAX jax_threefry_partitionable=True: bits32(i) = fold(threefry2x32((0,42),(0,i))),
// fold = o0 ^ o1; keep iff top bit == 0.  (verified round 2, absmax 0.0)
// Placement lesson (r11-r14): inline in agg is the cheapest home for the hashes.
// r15: fp16 h + v_pk_fma_f16. r16: unclamped main loop + precomputed
// (row*32, half2 ew) edge records -> steady-state iter ~35 VALU (was ~90).

typedef short bf16x8 __attribute__((ext_vector_type(8)));
typedef float f32x4  __attribute__((ext_vector_type(4)));

__device__ __forceinline__ uint32_t rotl32(uint32_t x, int d) {
    return (x << d) | (x >> (32 - d));
}

__device__ __forceinline__ void threefry2x32(uint32_t k0, uint32_t k1,
                                             uint32_t c0, uint32_t c1,
                                             uint32_t& o0, uint32_t& o1) {
    uint32_t ks2 = k0 ^ k1 ^ 0x1BD11BDAu;
    uint32_t x0 = c0 + k0, x1 = c1 + k1;
    x0 += x1; x1 = rotl32(x1, 13); x1 ^= x0;
    x0 += x1; x1 = rotl32(x1, 15); x1 ^= x0;
    x0 += x1; x1 = rotl32(x1, 26); x1 ^= x0;
    x0 += x1; x1 = rotl32(x1, 6);  x1 ^= x0;
    x0 += k1; x1 += ks2 + 1u;
    x0 += x1; x1 = rotl32(x1, 17); x1 ^= x0;
    x0 += x1; x1 = rotl32(x1, 29); x1 ^= x0;
    x0 += x1; x1 = rotl32(x1, 16); x1 ^= x0;
    x0 += x1; x1 = rotl32(x1, 24); x1 ^= x0;
    x0 += ks2; x1 += k0 + 2u;
    x0 += x1; x1 = rotl32(x1, 13); x1 ^= x0;
    x0 += x1; x1 = rotl32(x1, 15); x1 ^= x0;
    x0 += x1; x1 = rotl32(x1, 26); x1 ^= x0;
    x0 += x1; x1 = rotl32(x1, 6);  x1 ^= x0;
    x0 += k0; x1 += k1 + 3u;
    x0 += x1; x1 = rotl32(x1, 17); x1 ^= x0;
    x0 += x1; x1 = rotl32(x1, 29); x1 ^= x0;
    x0 += x1; x1 = rotl32(x1, 16); x1 ^= x0;
    x0 += x1; x1 = rotl32(x1, 24); x1 ^= x0;
    x0 += k1; x1 += ks2 + 4u;
    x0 += x1; x1 = rotl32(x1, 13); x1 ^= x0;
    x0 += x1; x1 = rotl32(x1, 15); x1 ^= x0;
    x0 += x1; x1 = rotl32(x1, 26); x1 ^= x0;
    x0 += x1; x1 = rotl32(x1, 6);  x1 ^= x0;
    x0 += ks2; x1 += k0 + 5u;
    o0 = x0; o1 = x1;
}

__device__ __forceinline__ bool dropout_keep(uint32_t i) {
    uint32_t o0, o1;
    threefry2x32(0u, 42u, 0u, i, o0, o1);
    return ((o0 ^ o1) & 0x80000000u) == 0u;
}

__device__ __forceinline__ uint32_t bf16_rne(float f) {   // fp32 -> bf16 bits (RNE)
    uint32_t u = __float_as_uint(f);
    return (u + 0x7FFFu + ((u >> 16) & 1u)) >> 16;
}

// blocks 0..15: W[k][n] f32 -> wt[n][k] bf16 (transposed, packed)
// blocks 16..: degsum = 0 (f64), sums = 0
__global__ __launch_bounds__(256) void k_init(const float* __restrict__ W,
                                              ushort* __restrict__ wt,
                                              double* degsum, float* sums) {
    int t = threadIdx.x;
    if (blockIdx.x < 16) {
        __shared__ float td[64][65];
        int kb = blockIdx.x & 3, nb = blockIdx.x >> 2;   // 4x4 tiles of 64x64
        int nl = t & 63, r4 = t >> 6;
#pragma unroll
        for (int i = 0; i < 16; i++) {
            int kl = r4 + 4 * i;
            td[kl][nl] = W[(size_t)(kb * 64 + kl) * 256 + nb * 64 + nl];
        }
        __syncthreads();
        int kp = t & 31, nl2 = t >> 5;
        uint32_t* wt32 = (uint32_t*)wt;
#pragma unroll
        for (int i = 0; i < 8; i++) {
            int n = nl2 + 8 * i;
            uint32_t p = bf16_rne(td[2 * kp][n]) | (bf16_rne(td[2 * kp + 1][n]) << 16);
            wt32[((size_t)(nb * 64 + n) * 256 + kb * 64 + 2 * kp) >> 1] = p;
        }
    } else {
        int i = (blockIdx.x - 16) * 256 + t;
        if (i < N_NODES) degsum[i] = 0.0;
        if (i < N_GRAPHS * D) sums[i] = 0.0f;
    }
}

// ONE f64 atomic per edge (count in high bits, sum ew in fraction)
__global__ __launch_bounds__(256) void k_edeg(const int* __restrict__ ei,
                                              const float* __restrict__ ew,
                                              double* __restrict__ degsum) {
    int e = blockIdx.x * 256 + threadIdx.x;   // grid is exactly 800000 threads
    int c = ei[N_EDGES + e];
    atomicAdd(&degsum[c], 4294967296.0 + (double)ew[e]);
}

// scan phase 1: degsum -> dinv + cnt(start[i]); per-block reduce of counts
__global__ __launch_bounds__(256) void k_scan1(const double* __restrict__ degsum,
                                               float* __restrict__ dinv,
                                               int* __restrict__ start,
                                               int* __restrict__ partial) {
    __shared__ int sd[256];
    int t = threadIdx.x;
    int i = blockIdx.x * 256 + t;
    int cnt = 0;
    if (i < N_NODES) {
        double val = degsum[i];
        cnt = (int)(val * (1.0 / 4294967296.0));          // exact
        float deg = (float)(val - (double)cnt * 4294967296.0) + 1.0f;  // +self-loop
        dinv[i] = rsqrtf(deg);                             // deg >= 1 always
        start[i] = cnt;
    }
    sd[t] = cnt;
    __syncthreads();
    for (int d = 128; d > 0; d >>= 1) {
        if (t < d) sd[t] += sd[t + d];
        __syncthreads();
    }
    if (t == 0) partial[blockIdx.x] = sd[0];
}

// scan phase 2+3 fused: every block redundantly scans the 196 partials in LDS,
// then does its own 256-chunk scan + base offset -> start/cursor (coalesced).
__global__ __launch_bounds__(256) void k_scan3(int* __restrict__ start,
                                               int* __restrict__ cursor,
                                               const int* __restrict__ partial) {
    __shared__ int sp[256];
    __shared__ int so[256];
    __shared__ int sd[256];
    int t = threadIdx.x;
    int pv = (t < NB_SCAN) ? partial[t] : 0;
    sp[t] = pv; so[t] = pv;
    __syncthreads();
    for (int d = 1; d < 256; d <<= 1) {
        int u = (t >= d) ? sp[t - d] : 0;
        __syncthreads();
        sp[t] += u;
        __syncthreads();
    }
    int base = sp[blockIdx.x] - so[blockIdx.x];    // exclusive prefix of this block

    int i = blockIdx.x * 256 + t;
    int v = (i < N_NODES) ? start[i] : 0;
    sd[t] = v;
    __syncthreads();
    for (int d = 1; d < 256; d <<= 1) {
        int u = (t >= d) ? sd[t - d] : 0;
        __syncthreads();
        sd[t] += u;
        __syncthreads();
    }
    int val = base + sd[t] - v;                    // exclusive prefix
    if (i < N_NODES) {
        start[i] = val;
        cursor[i] = val;
    } else if (i == N_NODES) {
        start[N_NODES] = val;                      // == grand total
    }
}

// scatter each edge's (row*32, half2(ew,ew)) into its CSR slot:
// pre-scaled gather index (no mul in agg) + pre-converted fp16 weight
// (no cvt in agg's hot loop).
__global__ __launch_bounds__(256) void k_fill(const int* __restrict__ ei,
                                              const float* __restrict__ ew,
                                              int* __restrict__ cursor,
                                              int2* __restrict__ edge) {
    int e = blockIdx.x * 256 + threadIdx.x;   // grid is exactly 800000 threads
    int r = ei[e];
    int c = ei[N_EDGES + e];
    int pos = atomicAdd(&cursor[c], 1);
    __half2 hw = __float2half2_rn(ew[e]);
    edge[pos] = make_int2(r * 32, *(int*)&hw);
}

// ---------------- MFMA GEMM: h'(fp16) = dinv[row] * (x @ W1) ---------------
// MFMA inputs bf16; OUTPUT stored as fp16. Coalesced C-write via 8KB LDS.
__device__ __forceinline__ int swz(int row, int kByte) {
    return (row << 9) + (kByte ^ ((row & 7) << 4));
}

__global__ __launch_bounds__(256) void k_gemm(const float* __restrict__ x,
                                              const ushort* __restrict__ wt,
                                              const float* __restrict__ dinv,
                                              ushort* __restrict__ hb) {
    __shared__ __align__(16) char smem[73728];   // A:[0,32K) Bt:[32K,64K) C:[64K,72K)
    __shared__ float sdinv[64];
    int tid = threadIdx.x;
    int Mbase = blockIdx.x * 64;

    if (tid < 64) {
        int node = Mbase + tid; if (node >= N_NODES) node = N_NODES - 1;
        sdinv[tid] = dinv[node];
    }
    // ---- stage A: x[Mbase..+63][0..255] -> bf16, swizzled ----
    const float4* xv = (const float4*)x;
#pragma unroll
    for (int i = 0; i < 16; i++) {
        int f = tid + i * 256;        // flat float4 id, 0..4095
        int r = f >> 6;               // row 0..63
        int c4 = f & 63;              // float4 index -> k = 4*c4
        int node = Mbase + r; if (node >= N_NODES) node = N_NODES - 1;
        float4 v = xv[(size_t)node * 64 + c4];
        uint32_t p0 = bf16_rne(v.x) | (bf16_rne(v.y) << 16);
        uint32_t p1 = bf16_rne(v.z) | (bf16_rne(v.w) << 16);
        *(uint2*)(smem + swz(r, c4 * 8)) = make_uint2(p0, p1);
    }

    int l = tid & 63;
    int w = tid >> 6;
    int wr = w >> 1, wc = w & 1;          // wave grid 2x2, each 32x32
    int lr = l & 15;
    int kg = l >> 4;
    int drow = (l >> 4) * 4;
    int dcol = l & 15;
    const uint4* wt4 = (const uint4*)wt;  // 16B units; 32 per 512B row
    ushort* c_lds = (ushort*)(smem + 65536);   // [64][64] fp16 tile

    for (int nb = 0; nb < 4; nb++) {
        // ---- stage Bt tile: wt rows nb*64..+63 (coalesced uint4 copy) ----
#pragma unroll
        for (int i = 0; i < 8; i++) {
            int f = tid + i * 256;    // 0..2047 uint4
            int r = f >> 5;           // row 0..63
            int c = f & 31;           // 16B chunk
            uint4 v = wt4[(size_t)(nb * 64 + r) * 32 + c];
            *(uint4*)(smem + 32768 + swz(r, c * 16)) = v;
        }
        __syncthreads();              // Bt ready; prev copy-out done

        f32x4 acc00 = {0.f, 0.f, 0.f, 0.f};
        f32x4 acc01 = acc00, acc10 = acc00, acc11 = acc00;
#pragma unroll
        for (int ks = 0; ks < 8; ks++) {
            int kB = ks * 64 + kg * 16;
            bf16x8 a0 = *(const bf16x8*)(smem + swz(wr * 32 + lr, kB));
            bf16x8 a1 = *(const bf16x8*)(smem + swz(wr * 32 + 16 + lr, kB));
            bf16x8 b0 = *(const bf16x8*)(smem + 32768 + swz(wc * 32 + lr, kB));
            bf16x8 b1 = *(const bf16x8*)(smem + 32768 + swz(wc * 32 + 16 + lr, kB));
            acc00 = __builtin_amdgcn_mfma_f32_16x16x32_bf16(a0, b0, acc00, 0, 0, 0);
            acc01 = __builtin_amdgcn_mfma_f32_16x16x32_bf16(a0, b1, acc01, 0, 0, 0);
            acc10 = __builtin_amdgcn_mfma_f32_16x16x32_bf16(a1, b0, acc10, 0, 0, 0);
            acc11 = __builtin_amdgcn_mfma_f32_16x16x32_bf16(a1, b1, acc11, 0, 0, 0);
        }
        // D layout: row=(l>>4)*4+r, col=l&15 (m89-verified); scale by dinv[row];
        // convert to fp16, stage into C_lds for coalesced writeback.
#pragma unroll
        for (int r = 0; r < 4; r++) {
            int lr0 = wr * 32 + drow + r;
            float s0 = sdinv[lr0], s1 = sdinv[lr0 + 16];
            int cc = wc * 32 + dcol;
            __half h00 = __float2half(acc00[r] * s0);
            __half h01 = __float2half(acc01[r] * s0);
            __half h10 = __float2half(acc10[r] * s1);
            __half h11 = __float2half(acc11[r] * s1);
            c_lds[lr0 * 64 + cc]             = *(ushort*)&h00;
            c_lds[lr0 * 64 + cc + 16]        = *(ushort*)&h01;
            c_lds[(lr0 + 16) * 64 + cc]      = *(ushort*)&h10;
            c_lds[(lr0 + 16) * 64 + cc + 16] = *(ushort*)&h11;
        }
        __syncthreads();              // C_lds complete
        // ---- coalesced copy-out: 512 uint4 (8KB), 2 per thread ----
#pragma unroll
        for (int i = 0; i < 2; i++) {
            int idx = tid + i * 256;  // 0..511
            int r = idx >> 3;         // row 0..63 (8 uint4 per 128B row segment)
            int c16 = idx & 7;
            int node = Mbase + r;
            if (node < N_NODES)
                *(uint4*)((char*)hb + (size_t)node * 512 + nb * 128 + c16 * 16) =
                    ((const uint4*)c_lds)[idx];
        }
    }
}

// CSR aggregate, r16 structure: UNCLAMPED main loop (j,e wave-uniform, all 8
// slots valid -> no min/cmp/select, weights direct) + one clamped tail
// iteration. Pre-scaled row offsets, pre-converted half2 weights, packed
// fp16 FMA, edge prefetch, inline threefry, block-level LDS pool flush.
__device__ __forceinline__ void fma8h(__half2* a, uint4 u, __half2 w) {
    a[0] = __hfma2(*(__half2*)&u.x, w, a[0]);
    a[1] = __hfma2(*(__half2*)&u.y, w, a[1]);
    a[2] = __hfma2(*(__half2*)&u.z, w, a[2]);
    a[3] = __hfma2(*(__half2*)&u.w, w, a[3]);
}

__global__ __launch_bounds__(256) void k_agg(const int* __restrict__ start,
                                             const int2* __restrict__ edge,
                                             const ushort* __restrict__ hb,
                                             const float* __restrict__ dinv,
                                             const float* __restrict__ b1,
                                             const int* __restrict__ gidx,
                                             float* __restrict__ sums) {
    __shared__ float ls[4][256];
    int wid = threadIdx.x >> 6;
    int l = threadIdx.x & 63;
    int half = l >> 5;                     // 0: even edge slots, 1: odd
    int cl = l & 31;                       // 16B column chunk (cols 8cl..8cl+7)
    int n = blockIdx.x * 4 + wid;          // always < N_NODES
    const uint4* h16 = (const uint4*)hb;   // 32 uint4 per 512B row
    int s = start[n], e = start[n + 1];
    int last = e - 1;

    // independent loads issued early
    uint4 un = h16[(size_t)n * 32 + cl];
    float4 bv = ((const float4*)b1)[2 * cl + half];
    float dn = dinv[n];
    int gfirst = gidx[blockIdx.x * 4];
    int glast  = gidx[blockIdx.x * 4 + 3];

    int off = 4 * half;
    int col = 8 * cl + off;

    // first batch preload (clamped) — issue before the threefry block
    int j = s;
    int2 E0, E1, E2, E3;
    if (j < e) {
        int i0 = j + half;
        int x1 = i0 + 2, x2 = i0 + 4, x3 = i0 + 6;
        E0 = edge[i0 < last ? i0 : last];
        E1 = edge[x1 < last ? x1 : last];
        E2 = edge[x2 < last ? x2 : last];
        E3 = edge[x3 < last ? x3 : last];
    }

    // dropout factors: ~280 VALU instrs hidden under the in-flight loads
    uint32_t base = (uint32_t)n * D + (uint32_t)col;
    float m0 = dropout_keep(base + 0u) ? 2.f : 0.f;
    float m1 = dropout_keep(base + 1u) ? 2.f : 0.f;
    float m2 = dropout_keep(base + 2u) ? 2.f : 0.f;
    float m3 = dropout_keep(base + 3u) ? 2.f : 0.f;

    __half2 z = __float2half2_rn(0.f);
    __half2 A0[4] = {z, z, z, z}, A1[4] = {z, z, z, z};
    __half2 A2[4] = {z, z, z, z}, A3[4] = {z, z, z, z};

    // -------- main loop: batch fully valid, no clamps/selects --------
    for (; j + 8 <= e; j += 8) {
        uint4 u0 = h16[(size_t)(uint32_t)(E0.x + cl)];
        uint4 u1 = h16[(size_t)(uint32_t)(E1.x + cl)];
        uint4 u2 = h16[(size_t)(uint32_t)(E2.x + cl)];
        uint4 u3 = h16[(size_t)(uint32_t)(E3.x + cl)];
        __half2 w0 = *(__half2*)&E0.y;
        __half2 w1 = *(__half2*)&E1.y;
        __half2 w2 = *(__half2*)&E2.y;
        __half2 w3 = *(__half2*)&E3.y;
        // prefetch next batch (clamped; mins bind only before the tail)
        int jn = j + 8;
        if (jn < e) {
            int i0n = jn + half;
            int y1 = i0n + 2, y2 = i0n + 4, y3 = i0n + 6;
            E0 = edge[i0n < last ? i0n : last];
            E1 = edge[y1 < last ? y1 : last];
            E2 = edge[y2 < last ? y2 : last];
            E3 = edge[y3 < last ? y3 : last];
        }
        fma8h(A0, u0, w0); fma8h(A1, u1, w1);
        fma8h(A2, u2, w2); fma8h(A3, u3, w3);
    }
    // -------- single clamped tail iteration --------
    if (j < e) {
        uint4 u0 = h16[(size_t)(uint32_t)(E0.x + cl)];
        uint4 u1 = h16[(size_t)(uint32_t)(E1.x + cl)];
        uint4 u2 = h16[(size_t)(uint32_t)(E2.x + cl)];
        uint4 u3 = h16[(size_t)(uint32_t)(E3.x + cl)];
        int x0 = j + half, x1 = x0 + 2, x2 = x0 + 4, x3 = x0 + 6;
        uint32_t b0 = x0 <= last ? (uint32_t)E0.y : 0u;
        uint32_t b1u = x1 <= last ? (uint32_t)E1.y : 0u;
        uint32_t b2 = x2 <= last ? (uint32_t)E2.y : 0u;
        uint32_t b3 = x3 <= last ? (uint32_t)E3.y : 0u;
        fma8h(A0, u0, *(__half2*)&b0); fma8h(A1, u1, *(__half2*)&b1u);
        fma8h(A2, u2, *(__half2*)&b2); fma8h(A3, u3, *(__half2*)&b3);
    }

    // combine the 4 accumulator sets in f32
    float full[8];
#pragma unroll
    for (int k = 0; k < 4; k++) {
        float lo = (__low2float(A0[k]) + __low2float(A1[k])) +
                   (__low2float(A2[k]) + __low2float(A3[k]));
        float hi = (__high2float(A0[k]) + __high2float(A1[k])) +
                   (__high2float(A2[k]) + __high2float(A3[k]));
        full[2 * k]     = lo;
        full[2 * k + 1] = hi;
    }
#pragma unroll
    for (int k = 0; k < 8; k++)
        full[k] += __shfl_xor(full[k], 32, 64);   // combine the two edge-halves

    // self-loop + bias + relu + dropout for this lane's 4 cols
    uint32_t q0 = half ? un.z : un.x;
    uint32_t q1 = half ? un.w : un.y;
    __half2 hq0 = *(__half2*)&q0;
    __half2 hq1 = *(__half2*)&q1;
    float hn0 = __low2float(hq0), hn1 = __high2float(hq0);
    float hn2 = __low2float(hq1), hn3 = __high2float(hq1);
    float v0 = fmaxf(dn * (full[off + 0] + hn0) + bv.x, 0.f) * m0;
    float v1 = fmaxf(dn * (full[off + 1] + hn1) + bv.y, 0.f) * m1;
    float v2 = fmaxf(dn * (full[off + 2] + hn2) + bv.z, 0.f) * m2;
    float v3 = fmaxf(dn * (full[off + 3] + hn3) + bv.w, 0.f) * m3;

    if (gfirst == glast) {                 // block-uniform branch (~99% of blocks)
        *(float4*)&ls[wid][col] = make_float4(v0, v1, v2, v3);
        __syncthreads();
        int t = threadIdx.x;
        float sv = (ls[0][t] + ls[1][t]) + (ls[2][t] + ls[3][t]);
        atomicAdd(&sums[(size_t)gfirst * D + t], sv);
    } else {                               // graph boundary inside block (rare)
        int g = gidx[n];
        float* sg = &sums[(size_t)g * D + col];
        atomicAdd(sg + 0, v0);
        atomicAdd(sg + 1, v1);
        atomicAdd(sg + 2, v2);
        atomicAdd(sg + 3, v3);
    }
}

// pooled = sums/cnt (cnt via binary search on sorted gidx); out = pooled@fcW+fcb
__global__ __launch_bounds__(256) void k_out(const float* __restrict__ sums,
                                             const int* __restrict__ gidx,
                                             const float* __restrict__ fcW,
                                             const float* __restrict__ fcb,
                                             float* __restrict__ out) {
    __shared__ int sh[2];
    __shared__ float p[D];
    int g = blockIdx.x, t = threadIdx.x;
    if (t == 0) {
        int lo = 0, hi = N_NODES;
        while (lo < hi) { int m = (lo + hi) >> 1; if (gidx[m] < g) lo = m + 1; else hi = m; }
        sh[0] = lo;
        int lo2 = lo; hi = N_NODES;
        while (lo2 < hi) { int m = (lo2 + hi) >> 1; if (gidx[m] < g + 1) lo2 = m + 1; else hi = m; }
        sh[1] = lo2;
    }
    __syncthreads();
    float c = fmaxf((float)(sh[1] - sh[0]), 1.0f);
    p[t] = sums[(size_t)g * D + t] / c;
    __syncthreads();
    if (t < D_OUT) {
        float acc = fcb[t];
        for (int k = 0; k < D; k++)
            acc = fmaf(p[k], fcW[k * D_OUT + t], acc);
        out[g * D_OUT + t] = acc;
    }
}

extern "C" void kernel_launch(void* const* d_in, const int* in_sizes, int n_in,
                              void* d_out, int out_size, void* d_ws, size_t ws_size,
                              hipStream_t stream) {
    const float* x   = (const float*)d_in[0];
    const int*   ei  = (const int*)d_in[1];
    const float* ew  = (const float*)d_in[2];
    const int*   gix = (const int*)d_in[3];
    const float* W1  = (const float*)d_in[4];
    const float* b1  = (const float*)d_in[5];
    const float* fcW = (const float*)d_in[6];
    const float* fcb = (const float*)d_in[7];
    float* out = (float*)d_out;

    float*   ws     = (float*)d_ws;
    float*   dinv   = ws;                                  //    65,536 f
    ushort*  hb     = (ushort*)(ws + 65536);               // 12.8M fp16
    int2*    edge   = (int2*)(ws + 65536 + 6400000);       //   800,000 int2
    int*     start  = (int*)(edge + N_EDGES);              //    65,536
    int*     cursor = start + 65536;                       //    65,536
    int*     partial    = cursor + 65536;                  //       256
    ushort*  wt     = (ushort*)(partial + 512);            //    65,536 us
    float*   sums   = (float*)(wt + 65536);                //    32,768 f
    double*  degsum = (double*)(sums + 32768);             //    50,000 f64
    // total ~35 MB

    k_init<<<NB_SCAN + 16, 256, 0, stream>>>(W1, wt, degsum, sums);
    k_edeg<<<N_EDGES / 256, 256, 0, stream>>>(ei, ew, degsum);
    k_scan1<<<NB_SCAN, 256, 0, stream>>>(degsum, dinv, start, partial);
    k_scan3<<<NB_SCAN, 256, 0, stream>>>(start, cursor, partial);
    k_fill<<<N_EDGES / 256, 256, 0, stream>>>(ei, ew, cursor, edge);
    k_gemm<<<(N_NODES + 63) / 64, 256, 0, stream>>>(x, wt, dinv, hb);
    k_agg<<<N_NODES / 4, 256, 0, stream>>>(start, edge, hb, dinv, b1, gix, sums);
    k_out<<<N_GRAPHS, 256, 0, stream>>>(sums, gix, fcW, fcb, out);
}

// Round 17
// 190.118 us; speedup vs baseline: 1.0684x; 1.0684x over previous
//
#include <hip/hip_runtime.h>
#include <hip/hip_fp16.h>
#include <stdint.h>

// Problem constants (match reference)
#define N_NODES  50000
#define N_EDGES  800000
#define D        256
#define D_OUT    16
#define N_GRAPHS 128
#define NB_SCAN  196        // 196*256 = 50176 >= N_NODES+1

// JAX jax_threefry_partitionable=True: bits32(i) = fold(threefry2x32((0,42),(0,i))),
// fold = o0 ^ o1; keep iff top bit == 0.  (verified round 2, absmax 0.0)
// r17: h stored as fp8 e4m3 (row = 256B) -> agg fetch floor ~halved; f32 accum.

typedef short bf16x8 __attribute__((ext_vector_type(8)));
typedef float f32x4  __attribute__((ext_vector_type(4)));
typedef float f32x2  __attribute__((ext_vector_type(2)));

__device__ __forceinline__ uint32_t rotl32(uint32_t x, int d) {
    return (x << d) | (x >> (32 - d));
}

__device__ __forceinline__ void threefry2x32(uint32_t k0, uint32_t k1,
                                             uint32_t c0, uint32_t c1,
                                             uint32_t& o0, uint32_t& o1) {
    uint32_t ks2 = k0 ^ k1 ^ 0x1BD11BDAu;
    uint32_t x0 = c0 + k0, x1 = c1 + k1;
    x0 += x1; x1 = rotl32(x1, 13); x1 ^= x0;
    x0 += x1; x1 = rotl32(x1, 15); x1 ^= x0;
    x0 += x1; x1 = rotl32(x1, 26); x1 ^= x0;
    x0 += x1; x1 = rotl32(x1, 6);  x1 ^= x0;
    x0 += k1; x1 += ks2 + 1u;
    x0 += x1; x1 = rotl32(x1, 17); x1 ^= x0;
    x0 += x1; x1 = rotl32(x1, 29); x1 ^= x0;
    x0 += x1; x1 = rotl32(x1, 16); x1 ^= x0;
    x0 += x1; x1 = rotl32(x1, 24); x1 ^= x0;
    x0 += ks2; x1 += k0 + 2u;
    x0 += x1; x1 = rotl32(x1, 13); x1 ^= x0;
    x0 += x1; x1 = rotl32(x1, 15); x1 ^= x0;
    x0 += x1; x1 = rotl32(x1, 26); x1 ^= x0;
    x0 += x1; x1 = rotl32(x1, 6);  x1 ^= x0;
    x0 += k0; x1 += k1 + 3u;
    x0 += x1; x1 = rotl32(x1, 17); x1 ^= x0;
    x0 += x1; x1 = rotl32(x1, 29); x1 ^= x0;
    x0 += x1; x1 = rotl32(x1, 16); x1 ^= x0;
    x0 += x1; x1 = rotl32(x1, 24); x1 ^= x0;
    x0 += k1; x1 += ks2 + 4u;
    x0 += x1; x1 = rotl32(x1, 13); x1 ^= x0;
    x0 += x1; x1 = rotl32(x1, 15); x1 ^= x0;
    x0 += x1; x1 = rotl32(x1, 26); x1 ^= x0;
    x0 += x1; x1 = rotl32(x1, 6);  x1 ^= x0;
    x0 += ks2; x1 += k0 + 5u;
    o0 = x0; o1 = x1;
}

__device__ __forceinline__ bool dropout_keep(uint32_t i) {
    uint32_t o0, o1;
    threefry2x32(0u, 42u, 0u, i, o0, o1);
    return ((o0 ^ o1) & 0x80000000u) == 0u;
}

__device__ __forceinline__ uint32_t bf16_rne(float f) {   // fp32 -> bf16 bits (RNE)
    uint32_t u = __float_as_uint(f);
    return (u + 0x7FFFu + ((u >> 16) & 1u)) >> 16;
}

// blocks 0..15: W[k][n] f32 -> wt[n][k] bf16 (transposed, packed)
// blocks 16..: degsum = 0 (f64), sums = 0, edge pad slots = 0
__global__ __launch_bounds__(256) void k_init(const float* __restrict__ W,
                                              ushort* __restrict__ wt,
                                              double* degsum, float* sums,
                                              int2* __restrict__ edge) {
    int t = threadIdx.x;
    if (blockIdx.x < 16) {
        __shared__ float td[64][65];
        int kb = blockIdx.x & 3, nb = blockIdx.x >> 2;   // 4x4 tiles of 64x64
        int nl = t & 63, r4 = t >> 6;
#pragma unroll
        for (int i = 0; i < 16; i++) {
            int kl = r4 + 4 * i;
            td[kl][nl] = W[(size_t)(kb * 64 + kl) * 256 + nb * 64 + nl];
        }
        __syncthreads();
        int kp = t & 31, nl2 = t >> 5;
        uint32_t* wt32 = (uint32_t*)wt;
#pragma unroll
        for (int i = 0; i < 8; i++) {
            int n = nl2 + 8 * i;
            uint32_t p = bf16_rne(td[2 * kp][n]) | (bf16_rne(td[2 * kp + 1][n]) << 16);
            wt32[((size_t)(nb * 64 + n) * 256 + kb * 64 + 2 * kp) >> 1] = p;
        }
    } else {
        int i = (blockIdx.x - 16) * 256 + t;
        if (i < N_NODES) degsum[i] = 0.0;
        if (i < N_GRAPHS * D) sums[i] = 0.0f;
        if (i < 16) edge[N_EDGES + i] = make_int2(0, 0);  // prefetch overrun pad
    }
}

// ONE f64 atomic per edge (count in high bits, sum ew in fraction)
__global__ __launch_bounds__(256) void k_edeg(const int* __restrict__ ei,
                                              const float* __restrict__ ew,
                                              double* __restrict__ degsum) {
    int e = blockIdx.x * 256 + threadIdx.x;   // grid is exactly 800000 threads
    int c = ei[N_EDGES + e];
    atomicAdd(&degsum[c], 4294967296.0 + (double)ew[e]);
}

// scan phase 1: degsum -> dinv + cnt(start[i]); per-block reduce of counts
__global__ __launch_bounds__(256) void k_scan1(const double* __restrict__ degsum,
                                               float* __restrict__ dinv,
                                               int* __restrict__ start,
                                               int* __restrict__ partial) {
    __shared__ int sd[256];
    int t = threadIdx.x;
    int i = blockIdx.x * 256 + t;
    int cnt = 0;
    if (i < N_NODES) {
        double val = degsum[i];
        cnt = (int)(val * (1.0 / 4294967296.0));          // exact
        float deg = (float)(val - (double)cnt * 4294967296.0) + 1.0f;  // +self-loop
        dinv[i] = rsqrtf(deg);                             // deg >= 1 always
        start[i] = cnt;
    }
    sd[t] = cnt;
    __syncthreads();
    for (int d = 128; d > 0; d >>= 1) {
        if (t < d) sd[t] += sd[t + d];
        __syncthreads();
    }
    if (t == 0) partial[blockIdx.x] = sd[0];
}

// scan phase 2+3 fused: redundant block-scan of the 196 partials in LDS, then
// per-block chunk scan -> start[] (EXCLUSIVE prefix). No cursor: k_fill bumps
// start in place; after fill, start[n] == end of node n (end-pointer trick).
__global__ __launch_bounds__(256) void k_scan3(int* __restrict__ start,
                                               const int* __restrict__ partial) {
    __shared__ int sp[256];
    __shared__ int so[256];
    __shared__ int sd[256];
    int t = threadIdx.x;
    int pv = (t < NB_SCAN) ? partial[t] : 0;
    sp[t] = pv; so[t] = pv;
    __syncthreads();
    for (int d = 1; d < 256; d <<= 1) {
        int u = (t >= d) ? sp[t - d] : 0;
        __syncthreads();
        sp[t] += u;
        __syncthreads();
    }
    int base = sp[blockIdx.x] - so[blockIdx.x];    // exclusive prefix of this block

    int i = blockIdx.x * 256 + t;
    int v = (i < N_NODES) ? start[i] : 0;
    sd[t] = v;
    __syncthreads();
    for (int d = 1; d < 256; d <<= 1) {
        int u = (t >= d) ? sd[t - d] : 0;
        __syncthreads();
        sd[t] += u;
        __syncthreads();
    }
    if (i < N_NODES) start[i] = base + sd[t] - v;  // exclusive prefix
}

// scatter each edge's (row*32, raw f32 ew) into its CSR slot; bumps start[]
__global__ __launch_bounds__(256) void k_fill(const int* __restrict__ ei,
                                              const float* __restrict__ ew,
                                              int* __restrict__ start,
                                              int2* __restrict__ edge) {
    int e = blockIdx.x * 256 + threadIdx.x;   // grid is exactly 800000 threads
    int r = ei[e];
    int c = ei[N_EDGES + e];
    int pos = atomicAdd(&start[c], 1);
    edge[pos] = make_int2(r * 32, __float_as_int(ew[e]));  // 32 uint2 per fp8 row
}

// ---------------- MFMA GEMM: h'(fp8 e4m3) = dinv[row] * (x @ W1) -----------
// MFMA inputs bf16; acc f32 -> fp16 LDS C-tile (r16 path) -> fp8 on copy-out.
__device__ __forceinline__ int swz(int row, int kByte) {
    return (row << 9) + (kByte ^ ((row & 7) << 4));
}

__global__ __launch_bounds__(256) void k_gemm(const float* __restrict__ x,
                                              const ushort* __restrict__ wt,
                                              const float* __restrict__ dinv,
                                              uint8_t* __restrict__ hb) {
    __shared__ __align__(16) char smem[73728];   // A:[0,32K) Bt:[32K,64K) C:[64K,72K)
    __shared__ float sdinv[64];
    int tid = threadIdx.x;
    int Mbase = blockIdx.x * 64;

    if (tid < 64) {
        int node = Mbase + tid; if (node >= N_NODES) node = N_NODES - 1;
        sdinv[tid] = dinv[node];
    }
    // ---- stage A: x[Mbase..+63][0..255] -> bf16, swizzled ----
    const float4* xv = (const float4*)x;
#pragma unroll
    for (int i = 0; i < 16; i++) {
        int f = tid + i * 256;        // flat float4 id, 0..4095
        int r = f >> 6;               // row 0..63
        int c4 = f & 63;              // float4 index -> k = 4*c4
        int node = Mbase + r; if (node >= N_NODES) node = N_NODES - 1;
        float4 v = xv[(size_t)node * 64 + c4];
        uint32_t p0 = bf16_rne(v.x) | (bf16_rne(v.y) << 16);
        uint32_t p1 = bf16_rne(v.z) | (bf16_rne(v.w) << 16);
        *(uint2*)(smem + swz(r, c4 * 8)) = make_uint2(p0, p1);
    }

    int l = tid & 63;
    int w = tid >> 6;
    int wr = w >> 1, wc = w & 1;          // wave grid 2x2, each 32x32
    int lr = l & 15;
    int kg = l >> 4;
    int drow = (l >> 4) * 4;
    int dcol = l & 15;
    const uint4* wt4 = (const uint4*)wt;  // 16B units; 32 per 512B row
    ushort* c_lds = (ushort*)(smem + 65536);   // [64][64] fp16 tile

    for (int nb = 0; nb < 4; nb++) {
        // ---- stage Bt tile: wt rows nb*64..+63 (coalesced uint4 copy) ----
#pragma unroll
        for (int i = 0; i < 8; i++) {
            int f = tid + i * 256;    // 0..2047 uint4
            int r = f >> 5;           // row 0..63
            int c = f & 31;           // 16B chunk
            uint4 v = wt4[(size_t)(nb * 64 + r) * 32 + c];
            *(uint4*)(smem + 32768 + swz(r, c * 16)) = v;
        }
        __syncthreads();              // Bt ready; prev copy-out done

        f32x4 acc00 = {0.f, 0.f, 0.f, 0.f};
        f32x4 acc01 = acc00, acc10 = acc00, acc11 = acc00;
#pragma unroll
        for (int ks = 0; ks < 8; ks++) {
            int kB = ks * 64 + kg * 16;
            bf16x8 a0 = *(const bf16x8*)(smem + swz(wr * 32 + lr, kB));
            bf16x8 a1 = *(const bf16x8*)(smem + swz(wr * 32 + 16 + lr, kB));
            bf16x8 b0 = *(const bf16x8*)(smem + 32768 + swz(wc * 32 + lr, kB));
            bf16x8 b1 = *(const bf16x8*)(smem + 32768 + swz(wc * 32 + 16 + lr, kB));
            acc00 = __builtin_amdgcn_mfma_f32_16x16x32_bf16(a0, b0, acc00, 0, 0, 0);
            acc01 = __builtin_amdgcn_mfma_f32_16x16x32_bf16(a0, b1, acc01, 0, 0, 0);
            acc10 = __builtin_amdgcn_mfma_f32_16x16x32_bf16(a1, b0, acc10, 0, 0, 0);
            acc11 = __builtin_amdgcn_mfma_f32_16x16x32_bf16(a1, b1, acc11, 0, 0, 0);
        }
        // D layout: row=(l>>4)*4+r, col=l&15 (m89-verified); scale by dinv[row];
        // fp16 into C_lds (known-good r16 path).
#pragma unroll
        for (int r = 0; r < 4; r++) {
            int lr0 = wr * 32 + drow + r;
            float s0 = sdinv[lr0], s1 = sdinv[lr0 + 16];
            int cc = wc * 32 + dcol;
            __half h00 = __float2half(acc00[r] * s0);
            __half h01 = __float2half(acc01[r] * s0);
            __half h10 = __float2half(acc10[r] * s1);
            __half h11 = __float2half(acc11[r] * s1);
            c_lds[lr0 * 64 + cc]             = *(ushort*)&h00;
            c_lds[lr0 * 64 + cc + 16]        = *(ushort*)&h01;
            c_lds[(lr0 + 16) * 64 + cc]      = *(ushort*)&h10;
            c_lds[(lr0 + 16) * 64 + cc + 16] = *(ushort*)&h11;
        }
        __syncthreads();              // C_lds complete
        // ---- copy-out with fp16->fp8 convert: 512 uint2 (4KB), 2/thread ----
#pragma unroll
        for (int i = 0; i < 2; i++) {
            int idx = tid + i * 256;  // 0..511
            int r = idx >> 3;         // row 0..63
            int c8 = idx & 7;         // 8-col group
            uint4 v = ((const uint4*)c_lds)[idx];   // 8 fp16
            __half2* hp = (__half2*)&v;
            float f0 = __low2float(hp[0]), f1 = __high2float(hp[0]);
            float f2 = __low2float(hp[1]), f3 = __high2float(hp[1]);
            float f4 = __low2float(hp[2]), f5 = __high2float(hp[2]);
            float f6 = __low2float(hp[3]), f7 = __high2float(hp[3]);
            uint32_t w0 = __builtin_amdgcn_cvt_pk_fp8_f32(f0, f1, 0, false);
            w0 = __builtin_amdgcn_cvt_pk_fp8_f32(f2, f3, w0, true);
            uint32_t w1 = __builtin_amdgcn_cvt_pk_fp8_f32(f4, f5, 0, false);
            w1 = __builtin_amdgcn_cvt_pk_fp8_f32(f6, f7, w1, true);
            int node = Mbase + r;
            if (node < N_NODES)
                *(uint2*)(hb + (size_t)node * 256 + nb * 64 + c8 * 8) =
                    make_uint2(w0, w1);
        }
    }
}

// CSR aggregate (fp8 h, f32 accum): 8-edge batches, 8B/lane gathers,
// unguarded next-batch prefetch (padded edge array), inline threefry,
// block-level LDS pool flush. start[] is the post-fill end-pointer array.
__device__ __forceinline__ void fma8f(float* a, uint2 u, float w) {
    f32x2 p0 = __builtin_amdgcn_cvt_pk_f32_fp8(u.x, false);
    f32x2 p1 = __builtin_amdgcn_cvt_pk_f32_fp8(u.x, true);
    f32x2 p2 = __builtin_amdgcn_cvt_pk_f32_fp8(u.y, false);
    f32x2 p3 = __builtin_amdgcn_cvt_pk_f32_fp8(u.y, true);
    a[0] = fmaf(w, p0.x, a[0]); a[1] = fmaf(w, p0.y, a[1]);
    a[2] = fmaf(w, p1.x, a[2]); a[3] = fmaf(w, p1.y, a[3]);
    a[4] = fmaf(w, p2.x, a[4]); a[5] = fmaf(w, p2.y, a[5]);
    a[6] = fmaf(w, p3.x, a[6]); a[7] = fmaf(w, p3.y, a[7]);
}

__global__ __launch_bounds__(256) void k_agg(const int* __restrict__ start,
                                             const int2* __restrict__ edge,
                                             const uint8_t* __restrict__ hb,
                                             const float* __restrict__ dinv,
                                             const float* __restrict__ b1,
                                             const int* __restrict__ gidx,
                                             float* __restrict__ sums) {
    __shared__ float ls[4][256];
    int wid = threadIdx.x >> 6;
    int l = threadIdx.x & 63;
    int half = l >> 5;                     // 0: even edge slots, 1: odd
    int cl = l & 31;                       // 8B column chunk (cols 8cl..8cl+7)
    int n = blockIdx.x * 4 + wid;          // always < N_NODES
    const uint2* h8 = (const uint2*)hb;    // 32 uint2 per 256B row
    int e = start[n];                      // end-pointer array
    int s = (n == 0) ? 0 : start[n - 1];
    int last = e - 1;

    // independent loads issued early
    uint2 un = h8[(size_t)n * 32 + cl];
    float4 bv = ((const float4*)b1)[2 * cl + half];
    float dn = dinv[n];
    int gfirst = gidx[blockIdx.x * 4];
    int glast  = gidx[blockIdx.x * 4 + 3];

    int off = 4 * half;
    int col = 8 * cl + off;

    // first batch preload (unguarded: edge[] padded by 16 zero slots)
    int j = s;
    int2 E0, E1, E2, E3;
    if (j < e) {
        int i0 = j + half;
        E0 = edge[i0];
        E1 = edge[i0 + 2];
        E2 = edge[i0 + 4];
        E3 = edge[i0 + 6];
    }

    // dropout factors: threefry VALU hidden under the in-flight loads
    uint32_t base = (uint32_t)n * D + (uint32_t)col;
    float m0 = dropout_keep(base + 0u) ? 2.f : 0.f;
    float m1 = dropout_keep(base + 1u) ? 2.f : 0.f;
    float m2 = dropout_keep(base + 2u) ? 2.f : 0.f;
    float m3 = dropout_keep(base + 3u) ? 2.f : 0.f;

    float A0[8] = {0,0,0,0,0,0,0,0}, A1[8] = {0,0,0,0,0,0,0,0};

    // -------- main loop: batch fully valid, no clamps/selects --------
    for (; j + 8 <= e; j += 8) {
        uint2 u0 = h8[(size_t)(uint32_t)(E0.x + cl)];
        uint2 u1 = h8[(size_t)(uint32_t)(E1.x + cl)];
        uint2 u2 = h8[(size_t)(uint32_t)(E2.x + cl)];
        uint2 u3 = h8[(size_t)(uint32_t)(E3.x + cl)];
        float w0 = __int_as_float(E0.y);
        float w1 = __int_as_float(E1.y);
        float w2 = __int_as_float(E2.y);
        float w3 = __int_as_float(E3.y);
        // unguarded prefetch (reads at most edge[j+15]; array padded)
        int i0n = j + 8 + half;
        E0 = edge[i0n];
        E1 = edge[i0n + 2];
        E2 = edge[i0n + 4];
        E3 = edge[i0n + 6];
        fma8f(A0, u0, w0); fma8f(A1, u1, w1);
        fma8f(A0, u2, w2); fma8f(A1, u3, w3);
    }
    // -------- single masked tail iteration --------
    if (j < e) {
        uint2 u0 = h8[(size_t)(uint32_t)(E0.x + cl)];
        uint2 u1 = h8[(size_t)(uint32_t)(E1.x + cl)];
        uint2 u2 = h8[(size_t)(uint32_t)(E2.x + cl)];
        uint2 u3 = h8[(size_t)(uint32_t)(E3.x + cl)];
        int x0 = j + half, x1 = x0 + 2, x2 = x0 + 4, x3 = x0 + 6;
        float w0 = x0 <= last ? __int_as_float(E0.y) : 0.f;
        float w1 = x1 <= last ? __int_as_float(E1.y) : 0.f;
        float w2 = x2 <= last ? __int_as_float(E2.y) : 0.f;
        float w3 = x3 <= last ? __int_as_float(E3.y) : 0.f;
        fma8f(A0, u0, w0); fma8f(A1, u1, w1);
        fma8f(A0, u2, w2); fma8f(A1, u3, w3);
    }

    float full[8];
#pragma unroll
    for (int k = 0; k < 8; k++)
        full[k] = A0[k] + A1[k];
#pragma unroll
    for (int k = 0; k < 8; k++)
        full[k] += __shfl_xor(full[k], 32, 64);   // combine the two edge-halves

    // self-loop + bias + relu + dropout for this lane's 4 cols
    uint32_t word = half ? un.y : un.x;
    f32x2 q0 = __builtin_amdgcn_cvt_pk_f32_fp8(word, false);
    f32x2 q1 = __builtin_amdgcn_cvt_pk_f32_fp8(word, true);
    float v0 = fmaxf(dn * (full[off + 0] + q0.x) + bv.x, 0.f) * m0;
    float v1 = fmaxf(dn * (full[off + 1] + q0.y) + bv.y, 0.f) * m1;
    float v2 = fmaxf(dn * (full[off + 2] + q1.x) + bv.z, 0.f) * m2;
    float v3 = fmaxf(dn * (full[off + 3] + q1.y) + bv.w, 0.f) * m3;

    if (gfirst == glast) {                 // block-uniform branch (~99% of blocks)
        *(float4*)&ls[wid][col] = make_float4(v0, v1, v2, v3);
        __syncthreads();
        int t = threadIdx.x;
        float sv = (ls[0][t] + ls[1][t]) + (ls[2][t] + ls[3][t]);
        atomicAdd(&sums[(size_t)gfirst * D + t], sv);
    } else {                               // graph boundary inside block (rare)
        int g = gidx[n];
        float* sg = &sums[(size_t)g * D + col];
        atomicAdd(sg + 0, v0);
        atomicAdd(sg + 1, v1);
        atomicAdd(sg + 2, v2);
        atomicAdd(sg + 3, v3);
    }
}

// pooled = sums/cnt (cnt via binary search on sorted gidx); out = pooled@fcW+fcb
__global__ __launch_bounds__(256) void k_out(const float* __restrict__ sums,
                                             const int* __restrict__ gidx,
                                             const float* __restrict__ fcW,
                                             const float* __restrict__ fcb,
                                             float* __restrict__ out) {
    __shared__ int sh[2];
    __shared__ float p[D];
    int g = blockIdx.x, t = threadIdx.x;
    if (t == 0) {
        int lo = 0, hi = N_NODES;
        while (lo < hi) { int m = (lo + hi) >> 1; if (gidx[m] < g) lo = m + 1; else hi = m; }
        sh[0] = lo;
        int lo2 = lo; hi = N_NODES;
        while (lo2 < hi) { int m = (lo2 + hi) >> 1; if (gidx[m] < g + 1) lo2 = m + 1; else hi = m; }
        sh[1] = lo2;
    }
    __syncthreads();
    float c = fmaxf((float)(sh[1] - sh[0]), 1.0f);
    p[t] = sums[(size_t)g * D + t] / c;
    __syncthreads();
    if (t < D_OUT) {
        float acc = fcb[t];
        for (int k = 0; k < D; k++)
            acc = fmaf(p[k], fcW[k * D_OUT + t], acc);
        out[g * D_OUT + t] = acc;
    }
}

extern "C" void kernel_launch(void* const* d_in, const int* in_sizes, int n_in,
                              void* d_out, int out_size, void* d_ws, size_t ws_size,
                              hipStream_t stream) {
    const float* x   = (const float*)d_in[0];
    const int*   ei  = (const int*)d_in[1];
    const float* ew  = (const float*)d_in[2];
    const int*   gix = (const int*)d_in[3];
    const float* W1  = (const float*)d_in[4];
    const float* b1  = (const float*)d_in[5];
    const float* fcW = (const float*)d_in[6];
    const float* fcb = (const float*)d_in[7];
    float* out = (float*)d_out;

    float*   ws     = (float*)d_ws;
    float*   dinv   = ws;                                   //    65,536 f
    uint8_t* hb     = (uint8_t*)(ws + 65536);               // 12.8 MB fp8
    int2*    edge   = (int2*)(ws + 65536 + 3200000);        // 800,016 int2
    int*     start  = (int*)(edge + N_EDGES + 16);          //    65,536
    int*     partial    = start + 65536;                    //       256 (+pad)
    ushort*  wt     = (ushort*)(partial + 512);             //    65,536 us
    float*   sums   = (float*)(wt + 65536);                 //    32,768 f
    double*  degsum = (double*)(sums + 32768);              //    50,000 f64
    // total ~21 MB

    k_init<<<NB_SCAN + 16, 256, 0, stream>>>(W1, wt, degsum, sums, edge);
    k_edeg<<<N_EDGES / 256, 256, 0, stream>>>(ei, ew, degsum);
    k_scan1<<<NB_SCAN, 256, 0, stream>>>(degsum, dinv, start, partial);
    k_scan3<<<NB_SCAN, 256, 0, stream>>>(start, partial);
    k_fill<<<N_EDGES / 256, 256, 0, stream>>>(ei, ew, start, edge);
    k_gemm<<<(N_NODES + 63) / 64, 256, 0, stream>>>(x, wt, dinv, hb);
    k_agg<<<N_NODES / 4, 256, 0, stream>>>(start, edge, hb, dinv, b1, gix, sums);
    k_out<<<N_GRAPHS, 256, 0, stream>>>(sums, gix, fcW, fcb, out);
}

// Round 18
// 189.640 us; speedup vs baseline: 1.0711x; 1.0025x over previous
//
#include <hip/hip_runtime.h>
#include <hip/hip_fp16.h>
#include <stdint.h>

// Problem constants (match reference)
#define N_NODES  50000
#define N_EDGES  800000
#define D        256
#define D_OUT    16
#define N_GRAPHS 128
#define NB_SCAN  196        // 196*256 = 50176 >= N_NODES+1
#define GEMM_NB  782        // (N_NODES+63)/64
#define FILL_NB  3125       // N_EDGES/256

// JAX jax_threefry_partitionable=True: bits32(i) = fold(threefry2x32((0,42),(0,i))),
// fold = o0 ^ o1; keep iff top bit == 0.  (verified round 2, absmax 0.0)
// r17: fp8 h storage (agg fetch 187->87MB). r18: grid-partitioned fusion —
// [wt|edeg] and [gemm|fill] overlap independent work in single launches.

typedef short bf16x8 __attribute__((ext_vector_type(8)));
typedef float f32x4  __attribute__((ext_vector_type(4)));
typedef float f32x2  __attribute__((ext_vector_type(2)));

__device__ __forceinline__ uint32_t rotl32(uint32_t x, int d) {
    return (x << d) | (x >> (32 - d));
}

__device__ __forceinline__ void threefry2x32(uint32_t k0, uint32_t k1,
                                             uint32_t c0, uint32_t c1,
                                             uint32_t& o0, uint32_t& o1) {
    uint32_t ks2 = k0 ^ k1 ^ 0x1BD11BDAu;
    uint32_t x0 = c0 + k0, x1 = c1 + k1;
    x0 += x1; x1 = rotl32(x1, 13); x1 ^= x0;
    x0 += x1; x1 = rotl32(x1, 15); x1 ^= x0;
    x0 += x1; x1 = rotl32(x1, 26); x1 ^= x0;
    x0 += x1; x1 = rotl32(x1, 6);  x1 ^= x0;
    x0 += k1; x1 += ks2 + 1u;
    x0 += x1; x1 = rotl32(x1, 17); x1 ^= x0;
    x0 += x1; x1 = rotl32(x1, 29); x1 ^= x0;
    x0 += x1; x1 = rotl32(x1, 16); x1 ^= x0;
    x0 += x1; x1 = rotl32(x1, 24); x1 ^= x0;
    x0 += ks2; x1 += k0 + 2u;
    x0 += x1; x1 = rotl32(x1, 13); x1 ^= x0;
    x0 += x1; x1 = rotl32(x1, 15); x1 ^= x0;
    x0 += x1; x1 = rotl32(x1, 26); x1 ^= x0;
    x0 += x1; x1 = rotl32(x1, 6);  x1 ^= x0;
    x0 += k0; x1 += k1 + 3u;
    x0 += x1; x1 = rotl32(x1, 17); x1 ^= x0;
    x0 += x1; x1 = rotl32(x1, 29); x1 ^= x0;
    x0 += x1; x1 = rotl32(x1, 16); x1 ^= x0;
    x0 += x1; x1 = rotl32(x1, 24); x1 ^= x0;
    x0 += k1; x1 += ks2 + 4u;
    x0 += x1; x1 = rotl32(x1, 13); x1 ^= x0;
    x0 += x1; x1 = rotl32(x1, 15); x1 ^= x0;
    x0 += x1; x1 = rotl32(x1, 26); x1 ^= x0;
    x0 += x1; x1 = rotl32(x1, 6);  x1 ^= x0;
    x0 += ks2; x1 += k0 + 5u;
    o0 = x0; o1 = x1;
}

__device__ __forceinline__ bool dropout_keep(uint32_t i) {
    uint32_t o0, o1;
    threefry2x32(0u, 42u, 0u, i, o0, o1);
    return ((o0 ^ o1) & 0x80000000u) == 0u;
}

__device__ __forceinline__ uint32_t bf16_rne(float f) {   // fp32 -> bf16 bits (RNE)
    uint32_t u = __float_as_uint(f);
    return (u + 0x7FFFu + ((u >> 16) & 1u)) >> 16;
}

// FUSED: blocks 0..15 = W transpose to bf16 wt[n][k]; 16.. = edeg f64 atomics
// (degsum zeroed by memset before this launch).
__global__ __launch_bounds__(256) void k_prep(const float* __restrict__ W,
                                              ushort* __restrict__ wt,
                                              const int* __restrict__ ei,
                                              const float* __restrict__ ew,
                                              double* __restrict__ degsum) {
    int t = threadIdx.x;
    if (blockIdx.x < 16) {
        __shared__ float td[64][65];
        int kb = blockIdx.x & 3, nb = blockIdx.x >> 2;   // 4x4 tiles of 64x64
        int nl = t & 63, r4 = t >> 6;
#pragma unroll
        for (int i = 0; i < 16; i++) {
            int kl = r4 + 4 * i;
            td[kl][nl] = W[(size_t)(kb * 64 + kl) * 256 + nb * 64 + nl];
        }
        __syncthreads();
        int kp = t & 31, nl2 = t >> 5;
        uint32_t* wt32 = (uint32_t*)wt;
#pragma unroll
        for (int i = 0; i < 8; i++) {
            int n = nl2 + 8 * i;
            uint32_t p = bf16_rne(td[2 * kp][n]) | (bf16_rne(td[2 * kp + 1][n]) << 16);
            wt32[((size_t)(nb * 64 + n) * 256 + kb * 64 + 2 * kp) >> 1] = p;
        }
    } else {
        int e = (blockIdx.x - 16) * 256 + t;   // exactly 800000 threads
        int c = ei[N_EDGES + e];
        atomicAdd(&degsum[c], 4294967296.0 + (double)ew[e]);
    }
}

// scan phase 1: degsum -> dinv + cnt(start[i]); per-block reduce of counts
__global__ __launch_bounds__(256) void k_scan1(const double* __restrict__ degsum,
                                               float* __restrict__ dinv,
                                               int* __restrict__ start,
                                               int* __restrict__ partial) {
    __shared__ int sd[256];
    int t = threadIdx.x;
    int i = blockIdx.x * 256 + t;
    int cnt = 0;
    if (i < N_NODES) {
        double val = degsum[i];
        cnt = (int)(val * (1.0 / 4294967296.0));          // exact
        float deg = (float)(val - (double)cnt * 4294967296.0) + 1.0f;  // +self-loop
        dinv[i] = rsqrtf(deg);                             // deg >= 1 always
        start[i] = cnt;
    }
    sd[t] = cnt;
    __syncthreads();
    for (int d = 128; d > 0; d >>= 1) {
        if (t < d) sd[t] += sd[t + d];
        __syncthreads();
    }
    if (t == 0) partial[blockIdx.x] = sd[0];
}

// scan phase 2+3 fused: redundant block-scan of the 196 partials in LDS, then
// per-block chunk scan -> start[] (EXCLUSIVE prefix). No cursor: k_fill bumps
// start in place; after fill, start[n] == end of node n (end-pointer trick).
__global__ __launch_bounds__(256) void k_scan3(int* __restrict__ start,
                                               const int* __restrict__ partial) {
    __shared__ int sp[256];
    __shared__ int so[256];
    __shared__ int sd[256];
    int t = threadIdx.x;
    int pv = (t < NB_SCAN) ? partial[t] : 0;
    sp[t] = pv; so[t] = pv;
    __syncthreads();
    for (int d = 1; d < 256; d <<= 1) {
        int u = (t >= d) ? sp[t - d] : 0;
        __syncthreads();
        sp[t] += u;
        __syncthreads();
    }
    int base = sp[blockIdx.x] - so[blockIdx.x];    // exclusive prefix of this block

    int i = blockIdx.x * 256 + t;
    int v = (i < N_NODES) ? start[i] : 0;
    sd[t] = v;
    __syncthreads();
    for (int d = 1; d < 256; d <<= 1) {
        int u = (t >= d) ? sd[t - d] : 0;
        __syncthreads();
        sd[t] += u;
        __syncthreads();
    }
    if (i < N_NODES) start[i] = base + sd[t] - v;  // exclusive prefix
}

__device__ __forceinline__ int swz(int row, int kByte) {
    return (row << 9) + (kByte ^ ((row & 7) << 4));
}

// FUSED main: blocks 0..781 = MFMA GEMM (h' fp8 = dinv[row]*(x@W1));
// blocks 782.. = CSR fill. Independent work; fill's atomic-stalled waves
// co-schedule with gemm's MFMA waves (separate pipes).
__global__ __launch_bounds__(256) void k_main(const float* __restrict__ x,
                                              const ushort* __restrict__ wt,
                                              const float* __restrict__ dinv,
                                              uint8_t* __restrict__ hb,
                                              const int* __restrict__ ei,
                                              const float* __restrict__ ew,
                                              int* __restrict__ start,
                                              int2* __restrict__ edge) {
    __shared__ __align__(16) char smem[73728];   // A:[0,32K) Bt:[32K,64K) C:[64K,72K)
    __shared__ float sdinv[64];
    int tid = threadIdx.x;

    if (blockIdx.x >= GEMM_NB) {
        // ---------------- fill path ----------------
        int e = (blockIdx.x - GEMM_NB) * 256 + tid;   // exactly 800000 threads
        int r = ei[e];
        int c = ei[N_EDGES + e];
        int pos = atomicAdd(&start[c], 1);
        edge[pos] = make_int2(r * 32, __float_as_int(ew[e]));  // 32 uint2/row
        return;
    }

    // ---------------- gemm path ----------------
    int Mbase = blockIdx.x * 64;
    if (tid < 64) {
        int node = Mbase + tid; if (node >= N_NODES) node = N_NODES - 1;
        sdinv[tid] = dinv[node];
    }
    // stage A: x[Mbase..+63][0..255] -> bf16, swizzled
    const float4* xv = (const float4*)x;
#pragma unroll
    for (int i = 0; i < 16; i++) {
        int f = tid + i * 256;        // flat float4 id, 0..4095
        int r = f >> 6;               // row 0..63
        int c4 = f & 63;              // float4 index -> k = 4*c4
        int node = Mbase + r; if (node >= N_NODES) node = N_NODES - 1;
        float4 v = xv[(size_t)node * 64 + c4];
        uint32_t p0 = bf16_rne(v.x) | (bf16_rne(v.y) << 16);
        uint32_t p1 = bf16_rne(v.z) | (bf16_rne(v.w) << 16);
        *(uint2*)(smem + swz(r, c4 * 8)) = make_uint2(p0, p1);
    }

    int l = tid & 63;
    int w = tid >> 6;
    int wr = w >> 1, wc = w & 1;          // wave grid 2x2, each 32x32
    int lr = l & 15;
    int kg = l >> 4;
    int drow = (l >> 4) * 4;
    int dcol = l & 15;
    const uint4* wt4 = (const uint4*)wt;  // 16B units; 32 per 512B row
    ushort* c_lds = (ushort*)(smem + 65536);   // [64][64] fp16 tile

    for (int nb = 0; nb < 4; nb++) {
        // stage Bt tile: wt rows nb*64..+63 (coalesced uint4 copy)
#pragma unroll
        for (int i = 0; i < 8; i++) {
            int f = tid + i * 256;    // 0..2047 uint4
            int r = f >> 5;           // row 0..63
            int c = f & 31;           // 16B chunk
            uint4 v = wt4[(size_t)(nb * 64 + r) * 32 + c];
            *(uint4*)(smem + 32768 + swz(r, c * 16)) = v;
        }
        __syncthreads();              // Bt ready; prev copy-out done

        f32x4 acc00 = {0.f, 0.f, 0.f, 0.f};
        f32x4 acc01 = acc00, acc10 = acc00, acc11 = acc00;
#pragma unroll
        for (int ks = 0; ks < 8; ks++) {
            int kB = ks * 64 + kg * 16;
            bf16x8 a0 = *(const bf16x8*)(smem + swz(wr * 32 + lr, kB));
            bf16x8 a1 = *(const bf16x8*)(smem + swz(wr * 32 + 16 + lr, kB));
            bf16x8 b0 = *(const bf16x8*)(smem + 32768 + swz(wc * 32 + lr, kB));
            bf16x8 b1 = *(const bf16x8*)(smem + 32768 + swz(wc * 32 + 16 + lr, kB));
            acc00 = __builtin_amdgcn_mfma_f32_16x16x32_bf16(a0, b0, acc00, 0, 0, 0);
            acc01 = __builtin_amdgcn_mfma_f32_16x16x32_bf16(a0, b1, acc01, 0, 0, 0);
            acc10 = __builtin_amdgcn_mfma_f32_16x16x32_bf16(a1, b0, acc10, 0, 0, 0);
            acc11 = __builtin_amdgcn_mfma_f32_16x16x32_bf16(a1, b1, acc11, 0, 0, 0);
        }
        // D layout row=(l>>4)*4+r, col=l&15 (m89); scale by dinv; fp16 C_lds
#pragma unroll
        for (int r = 0; r < 4; r++) {
            int lr0 = wr * 32 + drow + r;
            float s0 = sdinv[lr0], s1 = sdinv[lr0 + 16];
            int cc = wc * 32 + dcol;
            __half h00 = __float2half(acc00[r] * s0);
            __half h01 = __float2half(acc01[r] * s0);
            __half h10 = __float2half(acc10[r] * s1);
            __half h11 = __float2half(acc11[r] * s1);
            c_lds[lr0 * 64 + cc]             = *(ushort*)&h00;
            c_lds[lr0 * 64 + cc + 16]        = *(ushort*)&h01;
            c_lds[(lr0 + 16) * 64 + cc]      = *(ushort*)&h10;
            c_lds[(lr0 + 16) * 64 + cc + 16] = *(ushort*)&h11;
        }
        __syncthreads();              // C_lds complete
        // copy-out with fp16->fp8 convert: 512 uint2 (4KB), 2/thread
#pragma unroll
        for (int i = 0; i < 2; i++) {
            int idx = tid + i * 256;  // 0..511
            int r = idx >> 3;         // row 0..63
            int c8 = idx & 7;         // 8-col group
            uint4 v = ((const uint4*)c_lds)[idx];   // 8 fp16
            __half2* hp = (__half2*)&v;
            float f0 = __low2float(hp[0]), f1 = __high2float(hp[0]);
            float f2 = __low2float(hp[1]), f3 = __high2float(hp[1]);
            float f4 = __low2float(hp[2]), f5 = __high2float(hp[2]);
            float f6 = __low2float(hp[3]), f7 = __high2float(hp[3]);
            uint32_t w0 = __builtin_amdgcn_cvt_pk_fp8_f32(f0, f1, 0, false);
            w0 = __builtin_amdgcn_cvt_pk_fp8_f32(f2, f3, w0, true);
            uint32_t w1 = __builtin_amdgcn_cvt_pk_fp8_f32(f4, f5, 0, false);
            w1 = __builtin_amdgcn_cvt_pk_fp8_f32(f6, f7, w1, true);
            int node = Mbase + r;
            if (node < N_NODES)
                *(uint2*)(hb + (size_t)node * 256 + nb * 64 + c8 * 8) =
                    make_uint2(w0, w1);
        }
    }
}

// CSR aggregate (fp8 h, f32 accum): 8-edge batches, 8B/lane gathers,
// unguarded next-batch prefetch (padded edge array), inline threefry,
// block-level LDS pool flush. start[] is the post-fill end-pointer array.
__device__ __forceinline__ void fma8f(float* a, uint2 u, float w) {
    f32x2 p0 = __builtin_amdgcn_cvt_pk_f32_fp8(u.x, false);
    f32x2 p1 = __builtin_amdgcn_cvt_pk_f32_fp8(u.x, true);
    f32x2 p2 = __builtin_amdgcn_cvt_pk_f32_fp8(u.y, false);
    f32x2 p3 = __builtin_amdgcn_cvt_pk_f32_fp8(u.y, true);
    a[0] = fmaf(w, p0.x, a[0]); a[1] = fmaf(w, p0.y, a[1]);
    a[2] = fmaf(w, p1.x, a[2]); a[3] = fmaf(w, p1.y, a[3]);
    a[4] = fmaf(w, p2.x, a[4]); a[5] = fmaf(w, p2.y, a[5]);
    a[6] = fmaf(w, p3.x, a[6]); a[7] = fmaf(w, p3.y, a[7]);
}

__global__ __launch_bounds__(256) void k_agg(const int* __restrict__ start,
                                             const int2* __restrict__ edge,
                                             const uint8_t* __restrict__ hb,
                                             const float* __restrict__ dinv,
                                             const float* __restrict__ b1,
                                             const int* __restrict__ gidx,
                                             float* __restrict__ sums) {
    __shared__ float ls[4][256];
    int wid = threadIdx.x >> 6;
    int l = threadIdx.x & 63;
    int half = l >> 5;                     // 0: even edge slots, 1: odd
    int cl = l & 31;                       // 8B column chunk (cols 8cl..8cl+7)
    int n = blockIdx.x * 4 + wid;          // always < N_NODES
    const uint2* h8 = (const uint2*)hb;    // 32 uint2 per 256B row
    int e = start[n];                      // end-pointer array
    int s = (n == 0) ? 0 : start[n - 1];
    int last = e - 1;

    // independent loads issued early
    uint2 un = h8[(size_t)n * 32 + cl];
    float4 bv = ((const float4*)b1)[2 * cl + half];
    float dn = dinv[n];
    int gfirst = gidx[blockIdx.x * 4];
    int glast  = gidx[blockIdx.x * 4 + 3];

    int off = 4 * half;
    int col = 8 * cl + off;

    // first batch preload (unguarded: edge[] padded by 16 zero slots)
    int j = s;
    int2 E0, E1, E2, E3;
    if (j < e) {
        int i0 = j + half;
        E0 = edge[i0];
        E1 = edge[i0 + 2];
        E2 = edge[i0 + 4];
        E3 = edge[i0 + 6];
    }

    // dropout factors: threefry VALU hidden under the in-flight loads
    uint32_t base = (uint32_t)n * D + (uint32_t)col;
    float m0 = dropout_keep(base + 0u) ? 2.f : 0.f;
    float m1 = dropout_keep(base + 1u) ? 2.f : 0.f;
    float m2 = dropout_keep(base + 2u) ? 2.f : 0.f;
    float m3 = dropout_keep(base + 3u) ? 2.f : 0.f;

    float A0[8] = {0,0,0,0,0,0,0,0}, A1[8] = {0,0,0,0,0,0,0,0};

    // -------- main loop: batch fully valid, no clamps/selects --------
    for (; j + 8 <= e; j += 8) {
        uint2 u0 = h8[(size_t)(uint32_t)(E0.x + cl)];
        uint2 u1 = h8[(size_t)(uint32_t)(E1.x + cl)];
        uint2 u2 = h8[(size_t)(uint32_t)(E2.x + cl)];
        uint2 u3 = h8[(size_t)(uint32_t)(E3.x + cl)];
        float w0 = __int_as_float(E0.y);
        float w1 = __int_as_float(E1.y);
        float w2 = __int_as_float(E2.y);
        float w3 = __int_as_float(E3.y);
        // unguarded prefetch (reads at most edge[j+15]; array padded)
        int i0n = j + 8 + half;
        E0 = edge[i0n];
        E1 = edge[i0n + 2];
        E2 = edge[i0n + 4];
        E3 = edge[i0n + 6];
        fma8f(A0, u0, w0); fma8f(A1, u1, w1);
        fma8f(A0, u2, w2); fma8f(A1, u3, w3);
    }
    // -------- single masked tail iteration --------
    if (j < e) {
        uint2 u0 = h8[(size_t)(uint32_t)(E0.x + cl)];
        uint2 u1 = h8[(size_t)(uint32_t)(E1.x + cl)];
        uint2 u2 = h8[(size_t)(uint32_t)(E2.x + cl)];
        uint2 u3 = h8[(size_t)(uint32_t)(E3.x + cl)];
        int x0 = j + half, x1 = x0 + 2, x2 = x0 + 4, x3 = x0 + 6;
        float w0 = x0 <= last ? __int_as_float(E0.y) : 0.f;
        float w1 = x1 <= last ? __int_as_float(E1.y) : 0.f;
        float w2 = x2 <= last ? __int_as_float(E2.y) : 0.f;
        float w3 = x3 <= last ? __int_as_float(E3.y) : 0.f;
        fma8f(A0, u0, w0); fma8f(A1, u1, w1);
        fma8f(A0, u2, w2); fma8f(A1, u3, w3);
    }

    float full[8];
#pragma unroll
    for (int k = 0; k < 8; k++)
        full[k] = A0[k] + A1[k];
#pragma unroll
    for (int k = 0; k < 8; k++)
        full[k] += __shfl_xor(full[k], 32, 64);   // combine the two edge-halves

    // self-loop + bias + relu + dropout for this lane's 4 cols
    uint32_t word = half ? un.y : un.x;
    f32x2 q0 = __builtin_amdgcn_cvt_pk_f32_fp8(word, false);
    f32x2 q1 = __builtin_amdgcn_cvt_pk_f32_fp8(word, true);
    float v0 = fmaxf(dn * (full[off + 0] + q0.x) + bv.x, 0.f) * m0;
    float v1 = fmaxf(dn * (full[off + 1] + q0.y) + bv.y, 0.f) * m1;
    float v2 = fmaxf(dn * (full[off + 2] + q1.x) + bv.z, 0.f) * m2;
    float v3 = fmaxf(dn * (full[off + 3] + q1.y) + bv.w, 0.f) * m3;

    if (gfirst == glast) {                 // block-uniform branch (~99% of blocks)
        *(float4*)&ls[wid][col] = make_float4(v0, v1, v2, v3);
        __syncthreads();
        int t = threadIdx.x;
        float sv = (ls[0][t] + ls[1][t]) + (ls[2][t] + ls[3][t]);
        atomicAdd(&sums[(size_t)gfirst * D + t], sv);
    } else {                               // graph boundary inside block (rare)
        int g = gidx[n];
        float* sg = &sums[(size_t)g * D + col];
        atomicAdd(sg + 0, v0);
        atomicAdd(sg + 1, v1);
        atomicAdd(sg + 2, v2);
        atomicAdd(sg + 3, v3);
    }
}

// pooled = sums/cnt (cnt via binary search on sorted gidx); out = pooled@fcW+fcb
__global__ __launch_bounds__(256) void k_out(const float* __restrict__ sums,
                                             const int* __restrict__ gidx,
                                             const float* __restrict__ fcW,
                                             const float* __restrict__ fcb,
                                             float* __restrict__ out) {
    __shared__ int sh[2];
    __shared__ float p[D];
    int g = blockIdx.x, t = threadIdx.x;
    if (t == 0) {
        int lo = 0, hi = N_NODES;
        while (lo < hi) { int m = (lo + hi) >> 1; if (gidx[m] < g) lo = m + 1; else hi = m; }
        sh[0] = lo;
        int lo2 = lo; hi = N_NODES;
        while (lo2 < hi) { int m = (lo2 + hi) >> 1; if (gidx[m] < g + 1) lo2 = m + 1; else hi = m; }
        sh[1] = lo2;
    }
    __syncthreads();
    float c = fmaxf((float)(sh[1] - sh[0]), 1.0f);
    p[t] = sums[(size_t)g * D + t] / c;
    __syncthreads();
    if (t < D_OUT) {
        float acc = fcb[t];
        for (int k = 0; k < D; k++)
            acc = fmaf(p[k], fcW[k * D_OUT + t], acc);
        out[g * D_OUT + t] = acc;
    }
}

extern "C" void kernel_launch(void* const* d_in, const int* in_sizes, int n_in,
                              void* d_out, int out_size, void* d_ws, size_t ws_size,
                              hipStream_t stream) {
    const float* x   = (const float*)d_in[0];
    const int*   ei  = (const int*)d_in[1];
    const float* ew  = (const float*)d_in[2];
    const int*   gix = (const int*)d_in[3];
    const float* W1  = (const float*)d_in[4];
    const float* b1  = (const float*)d_in[5];
    const float* fcW = (const float*)d_in[6];
    const float* fcb = (const float*)d_in[7];
    float* out = (float*)d_out;

    float*   ws     = (float*)d_ws;
    float*   dinv   = ws;                                   //    65,536 f
    uint8_t* hb     = (uint8_t*)(ws + 65536);               // 12.8 MB fp8
    int2*    edge   = (int2*)(ws + 65536 + 3200000);        // 800,016 int2
    int*     start  = (int*)(edge + N_EDGES + 16);          //    65,536
    int*     partial    = start + 65536;                    //       256 (+pad)
    ushort*  wt     = (ushort*)(partial + 512);             //    65,536 us
    float*   sums   = (float*)(wt + 65536);                 //    32,768 f
    double*  degsum = (double*)(sums + 32768);              //    50,000 f64
    // total ~21 MB

    // per-call zero-init (replays don't re-poison)
    hipMemsetAsync(degsum, 0, N_NODES * sizeof(double), stream);
    hipMemsetAsync(sums, 0, N_GRAPHS * D * sizeof(float), stream);
    hipMemsetAsync(edge + N_EDGES, 0, 16 * sizeof(int2), stream);

    k_prep<<<16 + FILL_NB, 256, 0, stream>>>(W1, wt, ei, ew, degsum);
    k_scan1<<<NB_SCAN, 256, 0, stream>>>(degsum, dinv, start, partial);
    k_scan3<<<NB_SCAN, 256, 0, stream>>>(start, partial);
    k_main<<<GEMM_NB + FILL_NB, 256, 0, stream>>>(x, wt, dinv, hb, ei, ew, start, edge);
    k_agg<<<N_NODES / 4, 256, 0, stream>>>(start, edge, hb, dinv, b1, gix, sums);
    k_out<<<N_GRAPHS, 256, 0, stream>>>(sums, gix, fcW, fcb, out);
}